// Round 2
// baseline (124.053 us; speedup 1.0000x reference)
//
#include <hip/hip_runtime.h>
#include <math.h>

// Problem constants: FX=FY=48, CX=48, CY=36, H=72, W=96
#define NPIX 6912
#define CCH 16
#define LOG2E 1.4426950408889634f

// Workspace layout (floats):
//  rowdat : [N][20] at 0      {a_m * f1n[0..15], log2e*p1x, log2e*p1y, log2e*p1z, pad}
//           where a_m = exp(-|p1|^2/2)
//  f2n    : [16][N] at 20*N   (c-major normalized feature2)
//  col2   : [N][8]  at 36*N   {t0,t1,t2, -log2e*|t|^2/2,  q0,q1,q2, -log2e*|q|^2/2}
// total 44*N floats = 1.22 MB

__device__ __forceinline__ float fast_exp2(float x) { return __builtin_amdgcn_exp2f(x); }

__device__ __forceinline__ float block_reduce_256(float v, float* smem4) {
    #pragma unroll
    for (int o = 32; o > 0; o >>= 1) v += __shfl_down(v, o, 64);
    int lane = threadIdx.x & 63;
    int w = threadIdx.x >> 6;
    if (lane == 0) smem4[w] = v;
    __syncthreads();
    float r = 0.0f;
    if (threadIdx.x == 0) r = smem4[0] + smem4[1] + smem4[2] + smem4[3];
    return r;
}

__global__ __launch_bounds__(256)
void preproc_kernel(const float* __restrict__ f1, const float* __restrict__ f2,
                    const float* __restrict__ d1, const float* __restrict__ d2,
                    const float* __restrict__ pose, const float* __restrict__ pnz,
                    float* __restrict__ ws, float* __restrict__ out) {
    __shared__ float smem4[4];
    const int i = blockIdx.x * 256 + threadIdx.x;

    float* rowdat = ws;
    float* f2n    = ws + 20 * NPIX;
    float* col2   = ws + 36 * NPIX;

    // pose rows 0..2 (uniform -> scalar loads)
    float P[12];
    #pragma unroll
    for (int k = 0; k < 12; k++) P[k] = pose[k];
    // noisy pose = pose1_2 @ pose_noise, rows 0..2
    float Q[12];
    #pragma unroll
    for (int r = 0; r < 3; r++) {
        #pragma unroll
        for (int c = 0; c < 4; c++) {
            float s = 0.0f;
            #pragma unroll
            for (int k = 0; k < 4; k++) s = fmaf(pose[r * 4 + k], pnz[k * 4 + c], s);
            Q[r * 4 + c] = s;
        }
    }

    // back-projection ray: yz1 = (1, (u-48)/48, (v-36)/48)
    const float inv48 = 1.0f / 48.0f;
    const int u = i % 96;
    const int v = i / 96;
    const float y1 = fmaf((float)u, inv48, -1.0f);
    const float y2 = fmaf((float)v, inv48, -0.75f);

    // point cloud 1 + row factor a = exp(-|p1|^2/2)
    const float dep1 = d1[i];
    const float p1x = dep1, p1y = y1 * dep1, p1z = y2 * dep1;
    const float n1 = p1x * p1x + p1y * p1y + p1z * p1z;
    const float a_m = fast_exp2(-0.5f * LOG2E * n1);

    // point cloud 2 under both poses; fold -|.|^2/2 (log2 domain) into column consts
    const float dep2 = d2[i];
    const float a = dep2, b = y1 * dep2, c = y2 * dep2;
    float t0 = P[0] * a + P[1] * b + P[2]  * c + P[3];
    float t1 = P[4] * a + P[5] * b + P[6]  * c + P[7];
    float t2 = P[8] * a + P[9] * b + P[10] * c + P[11];
    float q0 = Q[0] * a + Q[1] * b + Q[2]  * c + Q[3];
    float q1 = Q[4] * a + Q[5] * b + Q[6]  * c + Q[7];
    float q2 = Q[8] * a + Q[9] * b + Q[10] * c + Q[11];
    float4 cA, cB;
    cA.x = t0; cA.y = t1; cA.z = t2;
    cA.w = -0.5f * LOG2E * (t0 * t0 + t1 * t1 + t2 * t2);
    cB.x = q0; cB.y = q1; cB.z = q2;
    cB.w = -0.5f * LOG2E * (q0 * q0 + q1 * q1 + q2 * q2);
    *(float4*)(col2 + (size_t)i * 8)     = cA;
    *(float4*)(col2 + (size_t)i * 8 + 4) = cB;

    // feature normalization + fold a_m into f1 row features
    float v1[CCH], v2[CCH];
    float s1 = 0.0f, s2 = 0.0f;
    #pragma unroll
    for (int cc = 0; cc < CCH; cc++) {
        v1[cc] = f1[cc * NPIX + i];
        v2[cc] = f2[cc * NPIX + i];
        s1 = fmaf(v1[cc], v1[cc], s1);
        s2 = fmaf(v2[cc], v2[cc], s2);
    }
    const float nrm1 = sqrtf(s1);
    const float nrm2 = sqrtf(s2);
    const float r1 = a_m / (nrm1 + 1e-8f);
    const float r2 = 1.0f / (nrm2 + 1e-8f);

    float vals[20];
    #pragma unroll
    for (int cc = 0; cc < CCH; cc++) {
        vals[cc] = v1[cc] * r1;
        f2n[cc * NPIX + i] = v2[cc] * r2;
    }
    vals[16] = LOG2E * p1x;
    vals[17] = LOG2E * p1y;
    vals[18] = LOG2E * p1z;
    vals[19] = 0.0f;
    #pragma unroll
    for (int k = 0; k < 5; k++)
        *(float4*)(rowdat + (size_t)i * 20 + k * 4) = *(float4*)(vals + k * 4);

    float tot = block_reduce_256(nrm1 + nrm2, smem4);
    if (threadIdx.x == 0) atomicAdd(out + 2, 100.0f * tot);
}

// tile: 128 rows x 256 cols per block; grid (27 col-blocks, 54 row-blocks)
__global__ __launch_bounds__(256)
void pair_loss_kernel(const float* __restrict__ ws, float* __restrict__ out) {
    __shared__ float tile[128 * 20];   // 10 KB
    __shared__ float smem4[4];

    const float* rowdat = ws;
    const float* f2n    = ws + 20 * NPIX;
    const float* col2   = ws + 36 * NPIX;

    const int t  = threadIdx.x;
    const int n  = blockIdx.x * 256 + t;   // column owned by this thread
    const int m0 = blockIdx.y * 128;       // row strip

    // column-resident registers
    float4 fr[4];
    #pragma unroll
    for (int k = 0; k < 4; k++) {
        fr[k].x = f2n[(4 * k + 0) * NPIX + n];
        fr[k].y = f2n[(4 * k + 1) * NPIX + n];
        fr[k].z = f2n[(4 * k + 2) * NPIX + n];
        fr[k].w = f2n[(4 * k + 3) * NPIX + n];
    }
    const float4 cA = *(const float4*)(col2 + (size_t)n * 8);
    const float4 cB = *(const float4*)(col2 + (size_t)n * 8 + 4);

    // stage 128 rows x 20 floats = 640 float4s (contiguous in global)
    {
        const float4* src = (const float4*)(rowdat + (size_t)m0 * 20);
        float4* dst = (float4*)tile;
        #pragma unroll
        for (int j = t; j < 640; j += 256) dst[j] = src[j];
    }
    __syncthreads();

    float acc = 0.0f;
    #pragma unroll 2
    for (int m = 0; m < 128; m++) {
        const float4* rq = (const float4*)(tile + m * 20);
        const float4 r0 = rq[0], r1 = rq[1], r2 = rq[2], r3 = rq[3], r4 = rq[4];

        float dot = r0.x * fr[0].x;
        dot = fmaf(r0.y, fr[0].y, dot);
        dot = fmaf(r0.z, fr[0].z, dot);
        dot = fmaf(r0.w, fr[0].w, dot);
        dot = fmaf(r1.x, fr[1].x, dot);
        dot = fmaf(r1.y, fr[1].y, dot);
        dot = fmaf(r1.z, fr[1].z, dot);
        dot = fmaf(r1.w, fr[1].w, dot);
        dot = fmaf(r2.x, fr[2].x, dot);
        dot = fmaf(r2.y, fr[2].y, dot);
        dot = fmaf(r2.z, fr[2].z, dot);
        dot = fmaf(r2.w, fr[2].w, dot);
        dot = fmaf(r3.x, fr[3].x, dot);
        dot = fmaf(r3.y, fr[3].y, dot);
        dot = fmaf(r3.z, fr[3].z, dot);
        dot = fmaf(r3.w, fr[3].w, dot);

        // cr2 = log2e*(p1.t - |t|^2/2); e1 = 2^cr2 = exp(-d1^2/2)/a_m (b folded in)
        float cr2 = fmaf(r4.x, cA.x, cA.w);
        cr2 = fmaf(r4.y, cA.y, cr2);
        cr2 = fmaf(r4.z, cA.z, cr2);
        float cq2 = fmaf(r4.x, cB.x, cB.w);
        cq2 = fmaf(r4.y, cB.y, cq2);
        cq2 = fmaf(r4.z, cB.z, cq2);

        const float e1 = fast_exp2(cr2);
        const float e2 = fast_exp2(cq2);
        acc = fmaf(e1 - e2, dot, acc);
    }

    float tot = block_reduce_256(acc, smem4);
    if (threadIdx.x == 0) {
        const float vcontrib = -tot * (1.0f / (float)NPIX);
        atomicAdd(out + 0, vcontrib);   // final_loss
        atomicAdd(out + 1, vcontrib);   // inner_neg
    }
}

extern "C" void kernel_launch(void* const* d_in, const int* in_sizes, int n_in,
                              void* d_out, int out_size, void* d_ws, size_t ws_size,
                              hipStream_t stream) {
    const float* feature1 = (const float*)d_in[0];
    const float* feature2 = (const float*)d_in[1];
    const float* depth1   = (const float*)d_in[2];
    const float* depth2   = (const float*)d_in[3];
    const float* pose1_2  = (const float*)d_in[4];
    const float* posenz   = (const float*)d_in[5];
    float* out = (float*)d_out;
    float* ws  = (float*)d_ws;

    hipMemsetAsync(d_out, 0, (size_t)out_size * sizeof(float), stream);

    preproc_kernel<<<27, 256, 0, stream>>>(feature1, feature2, depth1, depth2,
                                           pose1_2, posenz, ws, out);
    dim3 grid(27, 54);
    pair_loss_kernel<<<grid, 256, 0, stream>>>(ws, out);
}

// Round 4
// 104.581 us; speedup vs baseline: 1.1862x; 1.1862x over previous
//
#include <hip/hip_runtime.h>
#include <math.h>

// Problem constants: FX=FY=48, CX=48, CY=36, H=72, W=96, sigma2=1
#define NPIX 6912
#define LOG2E 1.4426950408889634f

typedef __fp16 h2 __attribute__((ext_vector_type(2)));

__device__ __forceinline__ float fast_exp2(float x) { return __builtin_amdgcn_exp2f(x); }

__device__ __forceinline__ h2 pack_h2(float a, float b) {
    return __builtin_amdgcn_cvt_pkrtz(a, b);
}

__device__ __forceinline__ float fdot2(h2 a, h2 b, float c) {
#if __has_builtin(__builtin_amdgcn_fdot2)
    return __builtin_amdgcn_fdot2(a, b, c, false);
#else
    return c + (float)a.x * (float)b.x + (float)a.y * (float)b.y;
#endif
}

__device__ __forceinline__ float block_reduce_256(float v, float* smem4) {
    __syncthreads();   // protect smem4 reuse across consecutive reductions
    #pragma unroll
    for (int o = 32; o > 0; o >>= 1) v += __shfl_down(v, o, 64);
    int lane = threadIdx.x & 63;
    int w = threadIdx.x >> 6;
    if (lane == 0) smem4[w] = v;
    __syncthreads();
    float r = 0.0f;
    if (threadIdx.x == 0) r = smem4[0] + smem4[1] + smem4[2] + smem4[3];
    return r;
}

// One fused kernel. Block = 768 columns (3/thread) x 64 rows. Grid (9, 108).
// Row m LDS record (12 floats, 48 B):
//   [0..7]  : 16 normalized f1 features packed as 8x half2
//   [8]     : w   = -log2e*|p1|^2/2
//   [9..11] : p~  = log2e * p1
// Column regs: ch[c][8] = f2 features (half2), cA = {t, -log2e*|t|^2/2}, cB likewise.
// e1 = 2^(w + cA.w + p~ . t) = exp(-|p1 - t|^2/2)  (exact factorization)
__global__ __launch_bounds__(256)
void fused_kernel(const float* __restrict__ f1, const float* __restrict__ f2,
                  const float* __restrict__ d1, const float* __restrict__ d2,
                  const float* __restrict__ pose, const float* __restrict__ pnz,
                  float* __restrict__ out) {
    __shared__ __align__(16) float rowlds[64 * 12];   // 3 KB
    __shared__ float smem4[4];

    const int t  = threadIdx.x;
    const int bx = blockIdx.x;        // 0..8
    const int m0 = blockIdx.y * 64;   // row strip

    // pose rows 0..2 (uniform -> scalar)
    float P[12];
    #pragma unroll
    for (int k = 0; k < 12; k++) P[k] = pose[k];
    float Q[12];
    #pragma unroll
    for (int r = 0; r < 3; r++) {
        #pragma unroll
        for (int c = 0; c < 4; c++) {
            float s = 0.0f;
            #pragma unroll
            for (int k = 0; k < 4; k++) s = fmaf(pose[r * 4 + k], pnz[k * 4 + c], s);
            Q[r * 4 + c] = s;
        }
    }

    const float inv48 = 1.0f / 48.0f;

    // ---------- stage row tile (threads 0..63, one row each) ----------
    if (t < 64) {
        const int r = m0 + t;
        const int u = r % 96, v = r / 96;
        const float y1 = fmaf((float)u, inv48, -1.0f);
        const float y2 = fmaf((float)v, inv48, -0.75f);
        const float dep = d1[r];
        const float px = dep, py = y1 * dep, pz = y2 * dep;
        const float n1 = px * px + py * py + pz * pz;
        float vv[16];
        float s = 0.0f;
        #pragma unroll
        for (int cc = 0; cc < 16; cc++) {
            vv[cc] = f1[cc * NPIX + r];
            s = fmaf(vv[cc], vv[cc], s);
        }
        const float rs = 1.0f / (sqrtf(s) + 1e-8f);
        float vals[12];
        #pragma unroll
        for (int j = 0; j < 8; j++)
            vals[j] = __builtin_bit_cast(float, pack_h2(vv[2 * j] * rs, vv[2 * j + 1] * rs));
        vals[8]  = -0.5f * LOG2E * n1;
        vals[9]  = LOG2E * px;
        vals[10] = LOG2E * py;
        vals[11] = LOG2E * pz;
        float4* dst = (float4*)(rowlds + t * 12);
        dst[0] = make_float4(vals[0], vals[1], vals[2],  vals[3]);
        dst[1] = make_float4(vals[4], vals[5], vals[6],  vals[7]);
        dst[2] = make_float4(vals[8], vals[9], vals[10], vals[11]);
    }

    // ---------- column data: 3 columns per thread ----------
    h2 ch[3][8];
    float4 cA[3], cB[3];
    float nsum = 0.0f;   // norm2 (+norm1 if y==0) contribution for fea_norm_sum

    #pragma unroll
    for (int c = 0; c < 3; c++) {
        const int n = bx * 768 + c * 256 + t;
        const int u = n % 96, v = n / 96;
        const float y1 = fmaf((float)u, inv48, -1.0f);
        const float y2 = fmaf((float)v, inv48, -0.75f);
        const float dep = d2[n];
        const float a = dep, b = y1 * dep, g = y2 * dep;
        const float t0 = P[0] * a + P[1] * b + P[2]  * g + P[3];
        const float t1 = P[4] * a + P[5] * b + P[6]  * g + P[7];
        const float t2 = P[8] * a + P[9] * b + P[10] * g + P[11];
        const float q0 = Q[0] * a + Q[1] * b + Q[2]  * g + Q[3];
        const float q1 = Q[4] * a + Q[5] * b + Q[6]  * g + Q[7];
        const float q2 = Q[8] * a + Q[9] * b + Q[10] * g + Q[11];
        cA[c] = make_float4(t0, t1, t2, -0.5f * LOG2E * (t0 * t0 + t1 * t1 + t2 * t2));
        cB[c] = make_float4(q0, q1, q2, -0.5f * LOG2E * (q0 * q0 + q1 * q1 + q2 * q2));

        float vv[16];
        float s = 0.0f;
        #pragma unroll
        for (int cc = 0; cc < 16; cc++) {
            vv[cc] = f2[cc * NPIX + n];
            s = fmaf(vv[cc], vv[cc], s);
        }
        const float nrm2 = sqrtf(s);
        const float rs = 1.0f / (nrm2 + 1e-8f);
        #pragma unroll
        for (int j = 0; j < 8; j++) ch[c][j] = pack_h2(vv[2 * j] * rs, vv[2 * j + 1] * rs);
        nsum += nrm2;
    }

    // y==0 blocks also accumulate norm1 over their column pixels (covers all N once)
    if (blockIdx.y == 0) {
        #pragma unroll
        for (int c = 0; c < 3; c++) {
            const int n = bx * 768 + c * 256 + t;
            float s = 0.0f;
            #pragma unroll
            for (int cc = 0; cc < 16; cc++) {
                const float x = f1[cc * NPIX + n];
                s = fmaf(x, x, s);
            }
            nsum += sqrtf(s);
        }
    }

    __syncthreads();

    // ---------- main loop: 64 rows x 3 columns ----------
    float acc = 0.0f;
    #pragma unroll 2
    for (int m = 0; m < 64; m++) {
        const float4* rq = (const float4*)(rowlds + m * 12);
        const float4 r0 = rq[0], r1 = rq[1], r2 = rq[2];
        h2 rh[8];
        rh[0] = __builtin_bit_cast(h2, r0.x);
        rh[1] = __builtin_bit_cast(h2, r0.y);
        rh[2] = __builtin_bit_cast(h2, r0.z);
        rh[3] = __builtin_bit_cast(h2, r0.w);
        rh[4] = __builtin_bit_cast(h2, r1.x);
        rh[5] = __builtin_bit_cast(h2, r1.y);
        rh[6] = __builtin_bit_cast(h2, r1.z);
        rh[7] = __builtin_bit_cast(h2, r1.w);

        #pragma unroll
        for (int c = 0; c < 3; c++) {
            float dot = fdot2(rh[0], ch[c][0], 0.0f);
            dot = fdot2(rh[1], ch[c][1], dot);
            dot = fdot2(rh[2], ch[c][2], dot);
            dot = fdot2(rh[3], ch[c][3], dot);
            dot = fdot2(rh[4], ch[c][4], dot);
            dot = fdot2(rh[5], ch[c][5], dot);
            dot = fdot2(rh[6], ch[c][6], dot);
            dot = fdot2(rh[7], ch[c][7], dot);

            float a1 = r2.x + cA[c].w;
            a1 = fmaf(r2.y, cA[c].x, a1);
            a1 = fmaf(r2.z, cA[c].y, a1);
            a1 = fmaf(r2.w, cA[c].z, a1);
            float a2 = r2.x + cB[c].w;
            a2 = fmaf(r2.y, cB[c].x, a2);
            a2 = fmaf(r2.z, cB[c].y, a2);
            a2 = fmaf(r2.w, cB[c].z, a2);

            const float e1 = fast_exp2(a1);
            const float e2 = fast_exp2(a2);
            acc = fmaf(e1 - e2, dot, acc);
        }
    }

    // ---------- reductions ----------
    float tot = block_reduce_256(acc, smem4);
    if (t == 0) {
        const float vc = -tot * (1.0f / (float)NPIX);
        atomicAdd(out + 0, vc);   // final_loss
        atomicAdd(out + 1, vc);   // inner_neg
    }
    if (blockIdx.y == 0) {
        float tn = block_reduce_256(nsum, smem4);
        if (t == 0) atomicAdd(out + 2, 100.0f * tn);
    }
}

extern "C" void kernel_launch(void* const* d_in, const int* in_sizes, int n_in,
                              void* d_out, int out_size, void* d_ws, size_t ws_size,
                              hipStream_t stream) {
    const float* feature1 = (const float*)d_in[0];
    const float* feature2 = (const float*)d_in[1];
    const float* depth1   = (const float*)d_in[2];
    const float* depth2   = (const float*)d_in[3];
    const float* pose1_2  = (const float*)d_in[4];
    const float* posenz   = (const float*)d_in[5];
    float* out = (float*)d_out;

    (void)hipMemsetAsync(d_out, 0, (size_t)out_size * sizeof(float), stream);

    dim3 grid(9, 108);
    fused_kernel<<<grid, 256, 0, stream>>>(feature1, feature2, depth1, depth2,
                                           pose1_2, posenz, out);
}